// Round 19
// baseline (189.475 us; speedup 1.0000x reference)
//
#include <hip/hip_runtime.h>
#include <hip/hip_bf16.h>
#include <cstdint>

// ---------------------------------------------------------------------------
// MultiHeadAttention: B=4 S=2048 D=1024 H=16 DQ=DV=64
//   1) prep: transpose Wq/Wk/Wv/Wo -> bf16 (N,K) only (q/k/v cast is fused
//      into the QKV GEMM -> saves ~96MB of HBM round-trip)
//   2) batched QKV GEMM, fp32 A converted in-kernel (T14 issue-early/
//      write-late reg staging), B via global_load_lds; BK=32 dbuf.
//      V epilogue: LDS-transpose -> coalesced 256B writes
//   3) flash attention: 32x32x16 MFMA, in-register P via cvt_pk +
//      permlane32_swap (no P LDS), m=0 exp2 softmax, psum ell
//   4) GEMM + bias -> fp32 out (bf16 A from attn, unchanged path)
// ---------------------------------------------------------------------------

typedef __attribute__((ext_vector_type(4))) float f32x4;
typedef __attribute__((ext_vector_type(16))) float f32x16;
typedef __attribute__((ext_vector_type(8))) short bf16x8;

#define GLB const __attribute__((address_space(1))) void*
#define LDS __attribute__((address_space(3))) void*

__device__ __forceinline__ ushort f2bf(float f) {
    uint32_t u = __builtin_bit_cast(uint32_t, f);
    u += 0x7fffu + ((u >> 16) & 1u);   // round-to-nearest-even
    return (ushort)(u >> 16);
}

// one v_cvt_pk_bf16_f32: packs 2 fp32 -> 2 bf16 in a u32 (RNE, lo = first)
__device__ __forceinline__ uint32_t cvt_pk_bf16(float lo, float hi) {
    uint32_t r;
    asm("v_cvt_pk_bf16_f32 %0, %1, %2" : "=v"(r) : "v"(lo), "v"(hi));
    return r;
}

// v_permlane32_swap: a.hi <-> b.lo
__device__ __forceinline__ void plswap(uint32_t& a, uint32_t& b) {
    auto r = __builtin_amdgcn_permlane32_swap(a, b, false, false);
    a = r[0];
    b = r[1];
}

// ---------------- stage 1: weight transposes only --------------------------
__global__ void prep(const float* __restrict__ w0, const float* __restrict__ w1,
                     const float* __restrict__ w2, const float* __restrict__ w3,
                     ushort* __restrict__ t0, ushort* __restrict__ t1,
                     ushort* __restrict__ t2, ushort* __restrict__ t3) {
    __shared__ float tile[64][65];
    const int wz = blockIdx.z, wy = blockIdx.y, wx = blockIdx.x;
    const float* in = wz == 0 ? w0 : wz == 1 ? w1 : wz == 2 ? w2 : w3;
    ushort* out     = wz == 0 ? t0 : wz == 1 ? t1 : wz == 2 ? t2 : t3;
    const int tx = threadIdx.x & 63, ty = threadIdx.x >> 6;
    const int nb = wx * 64, kb = wy * 64;
#pragma unroll
    for (int i = ty; i < 64; i += 4)
        tile[i][tx] = in[(size_t)(kb + i) * 1024 + nb + tx];
    __syncthreads();
#pragma unroll
    for (int i = ty; i < 64; i += 4)
        out[(size_t)(nb + i) * 1024 + kb + tx] = f2bf(tile[tx][i]);
}

// ---------------- stage 2: batched QKV GEMM, fp32 A fused-convert ----------
// SMEM ushort layout: A dbuf [2][128*40] (80B row stride: reads 2-way free,
// writes ~4-way), B dbuf [2][128*32] linear at offset 10240.
// grid (512, 3): y = projection (0=Q scaled, 1=K, 2=V transposed out).
__global__ __launch_bounds__(256) void gemm_qkv(const float* __restrict__ q_f,
                                                const float* __restrict__ k_f,
                                                const float* __restrict__ v_f,
                                                const ushort* __restrict__ WqT,
                                                const ushort* __restrict__ WkT,
                                                const ushort* __restrict__ WvT,
                                                const float* __restrict__ Wq_b,
                                                const float* __restrict__ Wk_b,
                                                const float* __restrict__ Wv_b,
                                                ushort* __restrict__ Qp,
                                                ushort* __restrict__ Kp,
                                                ushort* __restrict__ Vt,
                                                float qscale) {
    __shared__ ushort SMEM[18432];      // 36KB
    const int tid = threadIdx.x;
    const int lane = tid & 63;
    const int wave = tid >> 6, wr = wave >> 1, wc = wave & 1;
    const int r = lane & 15, g = lane >> 4;
    const int proj = blockIdx.y;
    const int id = blockIdx.x;
    const int xcd = id & 7, j = id >> 3;
    const int bx = j >> 3, by = xcd * 8 + (j & 7);
    const int mb = by * 128, nb = bx * 128;

    const float*  Af   = proj == 0 ? q_f : proj == 1 ? k_f : v_f;
    const ushort* BT   = proj == 0 ? WqT : proj == 1 ? WkT : WvT;
    const float*  bias = proj == 0 ? Wq_b : proj == 1 ? Wk_b : Wv_b;

    // A staging geometry: thread t -> row t>>1, k-half t&1 (16 fp32 = 4xfloat4)
    const int arow = tid >> 1, ahalf = tid & 1;
    const float* gA = Af + (size_t)(mb + arow) * 1024 + ahalf * 16;
    const int awb = arow * 80 + ahalf * 32;          // LDS byte offset (A)

    f32x4 acc[4][4] = {};

    // prologue: load+convert+write tile 0 into buf 0; stage B tile 0
    {
        float4 a0 = *(const float4*)(gA + 0);
        float4 a1 = *(const float4*)(gA + 4);
        float4 a2 = *(const float4*)(gA + 8);
        float4 a3 = *(const float4*)(gA + 12);
#pragma unroll
        for (int jj = 0; jj < 2; ++jj) {
            const int t = jj * 256 + tid;
            const int lo = 10240 + (jj * 256 + (tid & ~63)) * 8;
            __builtin_amdgcn_global_load_lds((GLB)(BT + (size_t)(nb + (t >> 2)) * 1024 + (t & 3) * 8),
                                             (LDS)(SMEM + lo), 16, 0, 0);
        }
        uint4 w0v, w1v;
        w0v.x = cvt_pk_bf16(a0.x, a0.y); w0v.y = cvt_pk_bf16(a0.z, a0.w);
        w0v.z = cvt_pk_bf16(a1.x, a1.y); w0v.w = cvt_pk_bf16(a1.z, a1.w);
        w1v.x = cvt_pk_bf16(a2.x, a2.y); w1v.y = cvt_pk_bf16(a2.z, a2.w);
        w1v.z = cvt_pk_bf16(a3.x, a3.y); w1v.w = cvt_pk_bf16(a3.z, a3.w);
        *(uint4*)((char*)SMEM + awb) = w0v;
        *(uint4*)((char*)SMEM + awb + 16) = w1v;
    }
    __syncthreads();

    for (int k0 = 0; k0 < 1024; k0 += 32) {
        const int cur = (k0 >> 5) & 1;
        const bool more = (k0 + 32 < 1024);
        // T14 issue-early: fp32 A loads for tile k+1
        float4 a0, a1, a2, a3;
        if (more) {
            const float* gn = gA + k0 + 32;
            a0 = *(const float4*)(gn + 0);
            a1 = *(const float4*)(gn + 4);
            a2 = *(const float4*)(gn + 8);
            a3 = *(const float4*)(gn + 12);
            // B stage for k+1 (async direct-to-LDS)
#pragma unroll
            for (int jj = 0; jj < 2; ++jj) {
                const int t = jj * 256 + tid;
                const int lo = 10240 + ((cur ^ 1) << 12) + (jj * 256 + (tid & ~63)) * 8;
                __builtin_amdgcn_global_load_lds((GLB)(BT + (size_t)(nb + (t >> 2)) * 1024 + k0 + 32 + (t & 3) * 8),
                                                 (LDS)(SMEM + lo), 16, 0, 0);
            }
        }

        const ushort* Ac = SMEM + (cur ? 5120 : 0);
        const ushort* Bc = SMEM + 10240 + (cur << 12);
        bf16x8 af[4], bfr[4];
#pragma unroll
        for (int i = 0; i < 4; ++i) {
            af[i]  = *(const bf16x8*)((const char*)Ac + (wr * 64 + i * 16 + r) * 80 + g * 16);
            bfr[i] = *(const bf16x8*)&Bc[(wc * 64 + i * 16 + r) * 32 + g * 8];
        }
        __builtin_amdgcn_s_setprio(1);
#pragma unroll
        for (int mi = 0; mi < 4; ++mi)
#pragma unroll
            for (int ni = 0; ni < 4; ++ni)
                acc[mi][ni] = __builtin_amdgcn_mfma_f32_16x16x32_bf16(af[mi], bfr[ni], acc[mi][ni], 0, 0, 0);
        __builtin_amdgcn_s_setprio(0);

        // T14 write-late: convert + LDS write (fp32 loads have had the MFMA
        // block to land)
        if (more) {
            const int wb = (cur ? 0 : 5120 * 2) + awb;   // bytes: buf^1 base
            uint4 w0v, w1v;
            w0v.x = cvt_pk_bf16(a0.x, a0.y); w0v.y = cvt_pk_bf16(a0.z, a0.w);
            w0v.z = cvt_pk_bf16(a1.x, a1.y); w0v.w = cvt_pk_bf16(a1.z, a1.w);
            w1v.x = cvt_pk_bf16(a2.x, a2.y); w1v.y = cvt_pk_bf16(a2.z, a2.w);
            w1v.z = cvt_pk_bf16(a3.x, a3.y); w1v.w = cvt_pk_bf16(a3.z, a3.w);
            *(uint4*)((char*)SMEM + wb) = w0v;
            *(uint4*)((char*)SMEM + wb + 16) = w1v;
        }
        __syncthreads();
    }

    if (proj < 2) {
        const float oscale = proj == 0 ? qscale : 1.0f;
        ushort* C = proj == 0 ? Qp : Kp;
#pragma unroll
        for (int ni = 0; ni < 4; ++ni) {
            const int col = nb + wc * 64 + ni * 16 + r;
            const float bv = bias[col];
#pragma unroll
            for (int mi = 0; mi < 4; ++mi) {
                const int m0 = mb + wr * 64 + mi * 16 + g * 4;
#pragma unroll
                for (int i = 0; i < 4; ++i)
                    C[(size_t)(m0 + i) * 1024 + col] = f2bf((acc[mi][ni][i] + bv) * oscale);
            }
        }
    } else {
        // V: LDS-transpose epilogue -> coalesced 256B Vt writes
#pragma unroll
        for (int ni = 0; ni < 4; ++ni) {
            const int colL = wc * 64 + ni * 16 + r;
            const int x8 = (colL & 7) << 3;
            const float bv = bias[nb + colL];
#pragma unroll
            for (int mi = 0; mi < 4; ++mi) {
                const int sL = wr * 64 + mi * 16 + g * 4;
                ushort4 o;
                o.x = f2bf(acc[mi][ni][0] + bv);
                o.y = f2bf(acc[mi][ni][1] + bv);
                o.z = f2bf(acc[mi][ni][2] + bv);
                o.w = f2bf(acc[mi][ni][3] + bv);
                *(ushort4*)&SMEM[colL * 128 + (sL ^ x8)] = o;
            }
        }
        __syncthreads();
        const int b = mb >> 11;
        const int sbase = mb & 2047;
#pragma unroll
        for (int p = 0; p < 8; ++p) {
            const int colL = p * 16 + (tid >> 4);
            const int cs = tid & 15;
            const int csx = cs ^ (colL & 7);
            const uint4 v = *(const uint4*)&SMEM[colL * 128 + csx * 8];
            const int gc = nb + colL;
            const int h = gc >> 6, dv = gc & 63;
            *(uint4*)&Vt[((((size_t)(b * 16 + h)) * 64 + dv) << 11) + sbase + cs * 8] = v;
        }
    }
}

// ---------------- stage 4: output GEMM + bias -> fp32 (bf16 A) -------------
#define GEMM_STAGE(A_, BT_, k0, Ad, Bd)                                             \
    _Pragma("unroll")                                                               \
    for (int jj = 0; jj < 2; ++jj) {                                                \
        const int t = jj * 256 + tid;                                               \
        const int lo = (jj * 256 + (tid & ~63)) * 8;                                \
        __builtin_amdgcn_global_load_lds((GLB)(A_  + (size_t)(mb + (t >> 2)) * 1024 + (k0) + (t & 3) * 8), (LDS)((Ad) + lo), 16, 0, 0); \
        __builtin_amdgcn_global_load_lds((GLB)(BT_ + (size_t)(nb + (t >> 2)) * 1024 + (k0) + (t & 3) * 8), (LDS)((Bd) + lo), 16, 0, 0); \
    }

__global__ __launch_bounds__(256) void gemm_out(const ushort* __restrict__ A_,
                                                const ushort* __restrict__ BT_,
                                                const float* __restrict__ bias,
                                                float* __restrict__ Cf) {
    __shared__ ushort SMEM[16384];
    const int tid = threadIdx.x;
    const int lane = tid & 63;
    const int wave = tid >> 6, wr = wave >> 1, wc = wave & 1;
    const int r = lane & 15, g = lane >> 4;
    const int id = blockIdx.x;
    const int xcd = id & 7, j = id >> 3;
    const int bx = j >> 3, by = xcd * 8 + (j & 7);
    const int mb = by * 128, nb = bx * 128;

    f32x4 acc[4][4] = {};
    GEMM_STAGE(A_, BT_, 0, SMEM, SMEM + 8192)
    __syncthreads();
    for (int k0 = 0; k0 < 1024; k0 += 32) {
        const int cur = (k0 >> 5) & 1;
        if (k0 + 32 < 1024) {
            GEMM_STAGE(A_, BT_, k0 + 32, SMEM + ((cur ^ 1) << 12), SMEM + 8192 + ((cur ^ 1) << 12))
        }
        const ushort* Ac = SMEM + (cur << 12);
        const ushort* Bc = SMEM + 8192 + (cur << 12);
        bf16x8 af[4], bfr[4];
#pragma unroll
        for (int i = 0; i < 4; ++i) {
            af[i]  = *(const bf16x8*)&Ac[(wr * 64 + i * 16 + r) * 32 + g * 8];
            bfr[i] = *(const bf16x8*)&Bc[(wc * 64 + i * 16 + r) * 32 + g * 8];
        }
        __builtin_amdgcn_s_setprio(1);
#pragma unroll
        for (int mi = 0; mi < 4; ++mi)
#pragma unroll
            for (int ni = 0; ni < 4; ++ni)
                acc[mi][ni] = __builtin_amdgcn_mfma_f32_16x16x32_bf16(af[mi], bfr[ni], acc[mi][ni], 0, 0, 0);
        __builtin_amdgcn_s_setprio(0);
        __syncthreads();
    }

#pragma unroll
    for (int ni = 0; ni < 4; ++ni) {
        const int col = nb + wc * 64 + ni * 16 + r;
        const float bv = bias[col];
#pragma unroll
        for (int mi = 0; mi < 4; ++mi) {
            const int m0 = mb + wr * 64 + mi * 16 + g * 4;
#pragma unroll
            for (int i = 0; i < 4; ++i)
                Cf[(size_t)(m0 + i) * 1024 + col] = acc[mi][ni][i] + bv;
        }
    }
}

// ---------------- stage 3: flash attention (32x32 MFMA, in-reg P) ----------
__global__ __launch_bounds__(512, 4) void attn_kernel(const ushort* __restrict__ Qp,
                                                      const ushort* __restrict__ Kp,
                                                      const ushort* __restrict__ Vt,
                                                      ushort* __restrict__ AO) {
    const int tid = threadIdx.x;
    const int lane = tid & 63, wave = tid >> 6;
    const int l31 = lane & 31, hl = lane >> 5;
    const int id = blockIdx.x;
    const int xcd = id & 7, j = id >> 3;
    const int qt = j & 7;
    const int grp = xcd * 8 + (j >> 3);      // (b,h) group 0..63
    const int h = grp & 15, b = grp >> 4;
    const int qrow = qt * 256 + wave * 32 + l31;

    const ushort* Qh = Qp + (size_t)b * 2048 * 1024 + h * 64;
    const ushort* Kh = Kp + (size_t)b * 2048 * 1024 + h * 64;
    const ushort* Vh = Vt + ((size_t)(b * 16 + h)) * 64 * 2048;

    __shared__ ushort Ks[2][64 * 64];
    __shared__ ushort Vs[2][64 * 64];

    const int srow = tid >> 3;
    const int scb  = ((tid & 7) * 16) ^ ((srow & 7) << 4);
    const int wlds = wave * 512;
    const ushort* gKn = Kh + (size_t)srow * 1024 + (scb >> 1) + 64 * 1024;
    const ushort* gVn = Vh + (size_t)srow * 2048 + (scb >> 1) + 64;

    int fro2[2][4];
#pragma unroll
    for (int t2 = 0; t2 < 2; ++t2)
#pragma unroll
        for (int c = 0; c < 4; ++c) {
            const int row = t2 * 32 + l31;
            fro2[t2][c] = row * 128 + ((c * 32 + hl * 16) ^ ((row & 7) << 4));
        }

    bf16x8 qf[4];
#pragma unroll
    for (int kq = 0; kq < 4; ++kq)
        qf[kq] = *(const bf16x8*)&Qh[(size_t)qrow * 1024 + kq * 16 + hl * 8];

    f32x16 o2[2] = {};
    float ell = 0.f;

    __builtin_amdgcn_global_load_lds((GLB)(gKn - 64 * 1024), (LDS)(Ks[0] + wlds), 16, 0, 0);
    __builtin_amdgcn_global_load_lds((GLB)(gVn - 64), (LDS)(Vs[0] + wlds), 16, 0, 0);
    __syncthreads();

    for (int t0 = 0; t0 < 2048; t0 += 64) {
        const int cur = (t0 >> 6) & 1;
        if (t0 + 64 < 2048) {
            __builtin_amdgcn_global_load_lds((GLB)gKn, (LDS)(Ks[cur ^ 1] + wlds), 16, 0, 0);
            __builtin_amdgcn_global_load_lds((GLB)gVn, (LDS)(Vs[cur ^ 1] + wlds), 16, 0, 0);
            gKn += 64 * 1024;
            gVn += 64;
        }

        const char* Kb = (const char*)Ks[cur];
        const char* Vb = (const char*)Vs[cur];

        bf16x8 pfr[2][2];
#pragma unroll
        for (int th = 0; th < 2; ++th) {
            f32x16 s = {};
            __builtin_amdgcn_s_setprio(1);
#pragma unroll
            for (int kq = 0; kq < 4; ++kq) {
                const bf16x8 kf = *(const bf16x8*)(Kb + fro2[th][kq]);
                s = __builtin_amdgcn_mfma_f32_32x32x16_bf16(kf, qf[kq], s, 0, 0, 0);
            }
            __builtin_amdgcn_s_setprio(0);

            float p[16];
#pragma unroll
            for (int i = 0; i < 16; ++i) p[i] = __builtin_amdgcn_exp2f(s[i]);
            ell += ((p[0] + p[1]) + (p[2] + p[3])) + ((p[4] + p[5]) + (p[6] + p[7]))
                 + ((p[8] + p[9]) + (p[10] + p[11])) + ((p[12] + p[13]) + (p[14] + p[15]));

            uint32_t w0 = cvt_pk_bf16(p[0], p[1]);
            uint32_t w1 = cvt_pk_bf16(p[2], p[3]);
            uint32_t w2 = cvt_pk_bf16(p[4], p[5]);
            uint32_t w3 = cvt_pk_bf16(p[6], p[7]);
            plswap(w0, w2);
            plswap(w1, w3);
            uint4 f0; f0.x = w0; f0.y = w1; f0.z = w2; f0.w = w3;
            pfr[th][0] = __builtin_bit_cast(bf16x8, f0);
            uint32_t w4 = cvt_pk_bf16(p[8], p[9]);
            uint32_t w5 = cvt_pk_bf16(p[10], p[11]);
            uint32_t w6 = cvt_pk_bf16(p[12], p[13]);
            uint32_t w7 = cvt_pk_bf16(p[14], p[15]);
            plswap(w4, w6);
            plswap(w5, w7);
            uint4 f1; f1.x = w4; f1.y = w5; f1.z = w6; f1.w = w7;
            pfr[th][1] = __builtin_bit_cast(bf16x8, f1);
        }

        __builtin_amdgcn_s_setprio(1);
#pragma unroll
        for (int vh = 0; vh < 2; ++vh)
#pragma unroll
            for (int kt = 0; kt < 4; ++kt) {
                const bf16x8 vf = *(const bf16x8*)(Vb + fro2[vh][kt]);
                o2[vh] = __builtin_amdgcn_mfma_f32_32x32x16_bf16(vf, pfr[kt >> 1][kt & 1], o2[vh], 0, 0, 0);
            }
        __builtin_amdgcn_s_setprio(0);

        __syncthreads();
    }

    ell += __shfl_xor(ell, 32);
    const float inv = 1.f / ell;
#pragma unroll
    for (int vh = 0; vh < 2; ++vh)
#pragma unroll
        for (int g4 = 0; g4 < 4; ++g4) {
            ushort4 o;
            o.x = f2bf(o2[vh][4 * g4 + 0] * inv);
            o.y = f2bf(o2[vh][4 * g4 + 1] * inv);
            o.z = f2bf(o2[vh][4 * g4 + 2] * inv);
            o.w = f2bf(o2[vh][4 * g4 + 3] * inv);
            const int dvb = 8 * g4 + 4 * hl + 32 * vh;
            *(ushort4*)&AO[(size_t)(b * 2048 + qrow) * 1024 + h * 64 + dvb] = o;
        }
}

// ---------------------------------------------------------------------------
extern "C" void kernel_launch(void* const* d_in, const int* in_sizes, int n_in,
                              void* d_out, int out_size, void* d_ws, size_t ws_size,
                              hipStream_t stream) {
    const float* q_f  = (const float*)d_in[0];
    const float* k_f  = (const float*)d_in[1];
    const float* v_f  = (const float*)d_in[2];
    const float* Wq_w = (const float*)d_in[3];
    const float* Wq_b = (const float*)d_in[4];
    const float* Wk_w = (const float*)d_in[5];
    const float* Wk_b = (const float*)d_in[6];
    const float* Wv_w = (const float*)d_in[7];
    const float* Wv_b = (const float*)d_in[8];
    const float* Wo_w = (const float*)d_in[9];
    const float* Wo_b = (const float*)d_in[10];
    float* out = (float*)d_out;
    char* ws = (char*)d_ws;

    const size_t MB = 1ull << 20;
    ushort* AO  = (ushort*)(ws);                 // 16 MB
    ushort* WqT = (ushort*)(ws + 48 * MB);       // 2 MB
    ushort* WkT = (ushort*)(ws + 50 * MB);       // 2 MB
    ushort* WvT = (ushort*)(ws + 52 * MB);       // 2 MB
    ushort* WoT = (ushort*)(ws + 54 * MB);       // 2 MB
    ushort* Qp  = (ushort*)(ws + 56 * MB);       // 16 MB
    ushort* Kp  = (ushort*)(ws + 72 * MB);       // 16 MB
    ushort* Vt  = (ushort*)(ws + 88 * MB);       // 16 MB  (end: 104 MB)

    prep<<<dim3(16, 16, 4), 256, 0, stream>>>(Wq_w, Wk_w, Wv_w, Wo_w,
                                              WqT, WkT, WvT, WoT);

    // fold attention scale (1/sqrt(2048)) and log2(e) into Q projection
    constexpr float QSCALE = (float)(1.4426950408889634 / 45.254833995939045);

    gemm_qkv<<<dim3(512, 3), 256, 0, stream>>>(q_f, k_f, v_f, WqT, WkT, WvT,
                                               Wq_b, Wk_b, Wv_b, Qp, Kp, Vt, QSCALE);

    attn_kernel<<<512, 512, 0, stream>>>(Qp, Kp, Vt, AO);

    gemm_out<<<512, 256, 0, stream>>>(AO, WoT, Wo_b, out);
}

// Round 20
// 188.158 us; speedup vs baseline: 1.0070x; 1.0070x over previous
//
#include <hip/hip_runtime.h>
#include <hip/hip_bf16.h>
#include <cstdint>

// ---------------------------------------------------------------------------
// MultiHeadAttention: B=4 S=2048 D=1024 H=16 DQ=DV=64   (round-16 proven)
//   1) prep: cast q/k/v fp32->bf16 + transpose Wq/Wk/Wv/Wo, single dispatch
//   2) batched QKV GEMM (BK=32 dbuf) -> Qp (pre-scaled log2e/sqrt(S)), Kp, Vt
//      V epilogue: LDS-transpose -> coalesced 256B writes
//   3) flash attention: 32x32x16 MFMA, in-register P via cvt_pk +
//      permlane32_swap (no P LDS), m=0 exp2 softmax, psum ell
//   4) GEMM + bias -> fp32 out
// NOTE: fp32-A fused-convert GEMM (round 19) REGRESSED: VGPR 68->116,
// MfmaUtil 26->16.6%, dur 70->127us. Do not re-land without occupancy fix.
// ones-MFMA ell is HW-falsified (rounds 6/11). m=0 softmax is proven safe.
// ---------------------------------------------------------------------------

typedef __attribute__((ext_vector_type(4))) float f32x4;
typedef __attribute__((ext_vector_type(16))) float f32x16;
typedef __attribute__((ext_vector_type(8))) short bf16x8;

#define GLB const __attribute__((address_space(1))) void*
#define LDS __attribute__((address_space(3))) void*

__device__ __forceinline__ ushort f2bf(float f) {
    uint32_t u = __builtin_bit_cast(uint32_t, f);
    u += 0x7fffu + ((u >> 16) & 1u);   // round-to-nearest-even
    return (ushort)(u >> 16);
}

// one v_cvt_pk_bf16_f32: packs 2 fp32 -> 2 bf16 in a u32 (RNE, lo = first)
__device__ __forceinline__ uint32_t cvt_pk_bf16(float lo, float hi) {
    uint32_t r;
    asm("v_cvt_pk_bf16_f32 %0, %1, %2" : "=v"(r) : "v"(lo), "v"(hi));
    return r;
}

// v_permlane32_swap: a.hi <-> b.lo
__device__ __forceinline__ void plswap(uint32_t& a, uint32_t& b) {
    auto r = __builtin_amdgcn_permlane32_swap(a, b, false, false);
    a = r[0];
    b = r[1];
}

// ---------------- stage 1: conversions + weight transposes, one dispatch ---
__global__ void prep(const float* __restrict__ qf, const float* __restrict__ kf,
                     const float* __restrict__ vf,
                     const float* __restrict__ w0, const float* __restrict__ w1,
                     const float* __restrict__ w2, const float* __restrict__ w3,
                     ushort* __restrict__ oq, ushort* __restrict__ ok,
                     ushort* __restrict__ ov,
                     ushort* __restrict__ t0, ushort* __restrict__ t1,
                     ushort* __restrict__ t2, ushort* __restrict__ t3, int n8) {
    __shared__ float tile[64][65];
    const int y = blockIdx.y;
    if (y < 3) {
        const float* in = y == 0 ? qf : y == 1 ? kf : vf;
        ushort* out     = y == 0 ? oq : y == 1 ? ok : ov;
        for (int i = blockIdx.x * blockDim.x + threadIdx.x; i < n8; i += gridDim.x * blockDim.x) {
            const float4 a = reinterpret_cast<const float4*>(in)[2 * i];
            const float4 b = reinterpret_cast<const float4*>(in)[2 * i + 1];
            uint4 o;
            o.x = cvt_pk_bf16(a.x, a.y);
            o.y = cvt_pk_bf16(a.z, a.w);
            o.z = cvt_pk_bf16(b.x, b.y);
            o.w = cvt_pk_bf16(b.z, b.w);
            reinterpret_cast<uint4*>(out)[i] = o;
        }
    } else {
        const int x = blockIdx.x;
        const int wz = x >> 8, wy = (x >> 4) & 15, wx = x & 15;
        const float* in = wz == 0 ? w0 : wz == 1 ? w1 : wz == 2 ? w2 : w3;
        ushort* out     = wz == 0 ? t0 : wz == 1 ? t1 : wz == 2 ? t2 : t3;
        const int tx = threadIdx.x & 63, ty = threadIdx.x >> 6;
        const int nb = wx * 64, kb = wy * 64;
#pragma unroll
        for (int i = ty; i < 64; i += 4)
            tile[i][tx] = in[(size_t)(kb + i) * 1024 + nb + tx];
        __syncthreads();
#pragma unroll
        for (int i = ty; i < 64; i += 4)
            out[(size_t)(nb + i) * 1024 + kb + tx] = f2bf(tile[tx][i]);
    }
}

// ---------------- GEMM: BK=32 dbuf, prefetch-1, 1 barrier per iter ---------
// SMEM layout (ushorts): [0,8192) = A dbuf (2x4096), [8192,16384) = B dbuf.
#define GEMM_STAGE(A_, BT_, k0, Ad, Bd)                                             \
    _Pragma("unroll")                                                               \
    for (int jj = 0; jj < 2; ++jj) {                                                \
        const int t = jj * 256 + tid;                                               \
        const int lo = (jj * 256 + (tid & ~63)) * 8;                                \
        __builtin_amdgcn_global_load_lds((GLB)(A_  + (size_t)(mb + (t >> 2)) * 1024 + (k0) + (t & 3) * 8), (LDS)((Ad) + lo), 16, 0, 0); \
        __builtin_amdgcn_global_load_lds((GLB)(BT_ + (size_t)(nb + (t >> 2)) * 1024 + (k0) + (t & 3) * 8), (LDS)((Bd) + lo), 16, 0, 0); \
    }

#define GEMM_BODY(A_, BT_, SM)                                                      \
    f32x4 acc[4][4] = {};                                                           \
    GEMM_STAGE(A_, BT_, 0, (SM), (SM) + 8192)                                       \
    __syncthreads();                                                                \
    for (int k0 = 0; k0 < 1024; k0 += 32) {                                         \
        const int cur = (k0 >> 5) & 1;                                              \
        if (k0 + 32 < 1024) {                                                       \
            GEMM_STAGE(A_, BT_, k0 + 32, (SM) + ((cur ^ 1) << 12), (SM) + 8192 + ((cur ^ 1) << 12)) \
        }                                                                           \
        const ushort* Ac = (SM) + (cur << 12);                                      \
        const ushort* Bc = (SM) + 8192 + (cur << 12);                               \
        bf16x8 af[4], bfr[4];                                                       \
        _Pragma("unroll")                                                           \
        for (int i = 0; i < 4; ++i) {                                               \
            af[i]  = *(const bf16x8*)&Ac[(wr * 64 + i * 16 + r) * 32 + g * 8];      \
            bfr[i] = *(const bf16x8*)&Bc[(wc * 64 + i * 16 + r) * 32 + g * 8];      \
        }                                                                           \
        __builtin_amdgcn_s_setprio(1);                                              \
        _Pragma("unroll")                                                           \
        for (int mi = 0; mi < 4; ++mi)                                              \
            _Pragma("unroll")                                                       \
            for (int ni = 0; ni < 4; ++ni)                                          \
                acc[mi][ni] = __builtin_amdgcn_mfma_f32_16x16x32_bf16(af[mi], bfr[ni], acc[mi][ni], 0, 0, 0); \
        __builtin_amdgcn_s_setprio(0);                                              \
        __syncthreads();                                                            \
    }

// ---------------- stage 2: batched QKV projection GEMM ---------------------
// grid (512, 3): y selects projection (0=Q scaled, 1=K, 2=V transposed out).
__global__ __launch_bounds__(256) void gemm_qkv(const ushort* __restrict__ qb,
                                                const ushort* __restrict__ kb,
                                                const ushort* __restrict__ vb,
                                                const ushort* __restrict__ WqT,
                                                const ushort* __restrict__ WkT,
                                                const ushort* __restrict__ WvT,
                                                const float* __restrict__ Wq_b,
                                                const float* __restrict__ Wk_b,
                                                const float* __restrict__ Wv_b,
                                                ushort* __restrict__ Qp,
                                                ushort* __restrict__ Kp,
                                                ushort* __restrict__ Vt,
                                                float qscale) {
    __shared__ ushort SMEM[16384];      // 32KB: staging dbuf, then V-transpose
    const int tid = threadIdx.x;
    const int lane = tid & 63;
    const int wave = tid >> 6, wr = wave >> 1, wc = wave & 1;
    const int r = lane & 15, g = lane >> 4;
    const int proj = blockIdx.y;
    const int id = blockIdx.x;
    const int xcd = id & 7, j = id >> 3;
    const int bx = j >> 3, by = xcd * 8 + (j & 7);
    const int mb = by * 128, nb = bx * 128;

    const ushort* A    = proj == 0 ? qb : proj == 1 ? kb : vb;
    const ushort* BT   = proj == 0 ? WqT : proj == 1 ? WkT : WvT;
    const float*  bias = proj == 0 ? Wq_b : proj == 1 ? Wk_b : Wv_b;

    GEMM_BODY(A, BT, SMEM)

    if (proj < 2) {
        const float oscale = proj == 0 ? qscale : 1.0f;
        ushort* C = proj == 0 ? Qp : Kp;
#pragma unroll
        for (int ni = 0; ni < 4; ++ni) {
            const int col = nb + wc * 64 + ni * 16 + r;
            const float bv = bias[col];
#pragma unroll
            for (int mi = 0; mi < 4; ++mi) {
                const int m0 = mb + wr * 64 + mi * 16 + g * 4;
#pragma unroll
                for (int i = 0; i < 4; ++i)
                    C[(size_t)(m0 + i) * 1024 + col] = f2bf((acc[mi][ni][i] + bv) * oscale);
            }
        }
    } else {
        // V: stash bf16 tile into LDS [col][s] (chunk-XOR swizzle), then
        // write Vt[b][h][dv][s] as contiguous 256B segments.
#pragma unroll
        for (int ni = 0; ni < 4; ++ni) {
            const int colL = wc * 64 + ni * 16 + r;        // local col 0..127
            const int x8 = (colL & 7) << 3;                // s-chunk xor
            const float bv = bias[nb + colL];
#pragma unroll
            for (int mi = 0; mi < 4; ++mi) {
                const int sL = wr * 64 + mi * 16 + g * 4;
                ushort4 o;
                o.x = f2bf(acc[mi][ni][0] + bv);
                o.y = f2bf(acc[mi][ni][1] + bv);
                o.z = f2bf(acc[mi][ni][2] + bv);
                o.w = f2bf(acc[mi][ni][3] + bv);
                *(ushort4*)&SMEM[colL * 128 + (sL ^ x8)] = o;
            }
        }
        __syncthreads();
        const int b = mb >> 11;
        const int sbase = mb & 2047;
#pragma unroll
        for (int p = 0; p < 8; ++p) {
            const int colL = p * 16 + (tid >> 4);          // 0..127
            const int cs = tid & 15;                       // s-chunk 0..15
            const int csx = cs ^ (colL & 7);
            const uint4 v = *(const uint4*)&SMEM[colL * 128 + csx * 8];
            const int gc = nb + colL;
            const int h = gc >> 6, dv = gc & 63;
            *(uint4*)&Vt[((((size_t)(b * 16 + h)) * 64 + dv) << 11) + sbase + cs * 8] = v;
        }
    }
}

// ---------------- stage 4: output GEMM + bias -> fp32 ----------------------
__global__ __launch_bounds__(256) void gemm_out(const ushort* __restrict__ A_,
                                                const ushort* __restrict__ BT_,
                                                const float* __restrict__ bias,
                                                float* __restrict__ Cf) {
    __shared__ ushort SMEM[16384];
    const int tid = threadIdx.x;
    const int lane = tid & 63;
    const int wave = tid >> 6, wr = wave >> 1, wc = wave & 1;
    const int r = lane & 15, g = lane >> 4;
    const int id = blockIdx.x;
    const int xcd = id & 7, j = id >> 3;
    const int bx = j >> 3, by = xcd * 8 + (j & 7);
    const int mb = by * 128, nb = bx * 128;

    GEMM_BODY(A_, BT_, SMEM)

#pragma unroll
    for (int ni = 0; ni < 4; ++ni) {
        const int col = nb + wc * 64 + ni * 16 + r;
        const float bv = bias[col];
#pragma unroll
        for (int mi = 0; mi < 4; ++mi) {
            const int m0 = mb + wr * 64 + mi * 16 + g * 4;
#pragma unroll
            for (int i = 0; i < 4; ++i)
                Cf[(size_t)(m0 + i) * 1024 + col] = acc[mi][ni][i] + bv;
        }
    }
}

// ---------------- stage 3: flash attention (32x32 MFMA, in-reg P) ----------
__global__ __launch_bounds__(512, 4) void attn_kernel(const ushort* __restrict__ Qp,
                                                      const ushort* __restrict__ Kp,
                                                      const ushort* __restrict__ Vt,
                                                      ushort* __restrict__ AO) {
    const int tid = threadIdx.x;
    const int lane = tid & 63, wave = tid >> 6;
    const int l31 = lane & 31, hl = lane >> 5;
    const int id = blockIdx.x;
    const int xcd = id & 7, j = id >> 3;
    const int qt = j & 7;
    const int grp = xcd * 8 + (j >> 3);      // (b,h) group 0..63
    const int h = grp & 15, b = grp >> 4;
    const int qrow = qt * 256 + wave * 32 + l31;

    const ushort* Qh = Qp + (size_t)b * 2048 * 1024 + h * 64;
    const ushort* Kh = Kp + (size_t)b * 2048 * 1024 + h * 64;
    const ushort* Vh = Vt + ((size_t)(b * 16 + h)) * 64 * 2048;

    __shared__ ushort Ks[2][64 * 64];
    __shared__ ushort Vs[2][64 * 64];

    const int srow = tid >> 3;
    const int scb  = ((tid & 7) * 16) ^ ((srow & 7) << 4);
    const int wlds = wave * 512;
    const ushort* gKn = Kh + (size_t)srow * 1024 + (scb >> 1) + 64 * 1024;
    const ushort* gVn = Vh + (size_t)srow * 2048 + (scb >> 1) + 64;

    int fro2[2][4];
#pragma unroll
    for (int t2 = 0; t2 < 2; ++t2)
#pragma unroll
        for (int c = 0; c < 4; ++c) {
            const int row = t2 * 32 + l31;
            fro2[t2][c] = row * 128 + ((c * 32 + hl * 16) ^ ((row & 7) << 4));
        }

    bf16x8 qf[4];
#pragma unroll
    for (int kq = 0; kq < 4; ++kq)
        qf[kq] = *(const bf16x8*)&Qh[(size_t)qrow * 1024 + kq * 16 + hl * 8];

    f32x16 o2[2] = {};
    float ell = 0.f;

    __builtin_amdgcn_global_load_lds((GLB)(gKn - 64 * 1024), (LDS)(Ks[0] + wlds), 16, 0, 0);
    __builtin_amdgcn_global_load_lds((GLB)(gVn - 64), (LDS)(Vs[0] + wlds), 16, 0, 0);
    __syncthreads();

    for (int t0 = 0; t0 < 2048; t0 += 64) {
        const int cur = (t0 >> 6) & 1;
        if (t0 + 64 < 2048) {
            __builtin_amdgcn_global_load_lds((GLB)gKn, (LDS)(Ks[cur ^ 1] + wlds), 16, 0, 0);
            __builtin_amdgcn_global_load_lds((GLB)gVn, (LDS)(Vs[cur ^ 1] + wlds), 16, 0, 0);
            gKn += 64 * 1024;
            gVn += 64;
        }

        const char* Kb = (const char*)Ks[cur];
        const char* Vb = (const char*)Vs[cur];

        bf16x8 pfr[2][2];
#pragma unroll
        for (int th = 0; th < 2; ++th) {
            f32x16 s = {};
            __builtin_amdgcn_s_setprio(1);
#pragma unroll
            for (int kq = 0; kq < 4; ++kq) {
                const bf16x8 kf = *(const bf16x8*)(Kb + fro2[th][kq]);
                s = __builtin_amdgcn_mfma_f32_32x32x16_bf16(kf, qf[kq], s, 0, 0, 0);
            }
            __builtin_amdgcn_s_setprio(0);

            float p[16];
#pragma unroll
            for (int i = 0; i < 16; ++i) p[i] = __builtin_amdgcn_exp2f(s[i]);
            ell += ((p[0] + p[1]) + (p[2] + p[3])) + ((p[4] + p[5]) + (p[6] + p[7]))
                 + ((p[8] + p[9]) + (p[10] + p[11])) + ((p[12] + p[13]) + (p[14] + p[15]));

            uint32_t w0 = cvt_pk_bf16(p[0], p[1]);
            uint32_t w1 = cvt_pk_bf16(p[2], p[3]);
            uint32_t w2 = cvt_pk_bf16(p[4], p[5]);
            uint32_t w3 = cvt_pk_bf16(p[6], p[7]);
            plswap(w0, w2);
            plswap(w1, w3);
            uint4 f0; f0.x = w0; f0.y = w1; f0.z = w2; f0.w = w3;
            pfr[th][0] = __builtin_bit_cast(bf16x8, f0);
            uint32_t w4 = cvt_pk_bf16(p[8], p[9]);
            uint32_t w5 = cvt_pk_bf16(p[10], p[11]);
            uint32_t w6 = cvt_pk_bf16(p[12], p[13]);
            uint32_t w7 = cvt_pk_bf16(p[14], p[15]);
            plswap(w4, w6);
            plswap(w5, w7);
            uint4 f1; f1.x = w4; f1.y = w5; f1.z = w6; f1.w = w7;
            pfr[th][1] = __builtin_bit_cast(bf16x8, f1);
        }

        __builtin_amdgcn_s_setprio(1);
#pragma unroll
        for (int vh = 0; vh < 2; ++vh)
#pragma unroll
            for (int kt = 0; kt < 4; ++kt) {
                const bf16x8 vf = *(const bf16x8*)(Vb + fro2[vh][kt]);
                o2[vh] = __builtin_amdgcn_mfma_f32_32x32x16_bf16(vf, pfr[kt >> 1][kt & 1], o2[vh], 0, 0, 0);
            }
        __builtin_amdgcn_s_setprio(0);

        __syncthreads();
    }

    ell += __shfl_xor(ell, 32);
    const float inv = 1.f / ell;
#pragma unroll
    for (int vh = 0; vh < 2; ++vh)
#pragma unroll
        for (int g4 = 0; g4 < 4; ++g4) {
            ushort4 o;
            o.x = f2bf(o2[vh][4 * g4 + 0] * inv);
            o.y = f2bf(o2[vh][4 * g4 + 1] * inv);
            o.z = f2bf(o2[vh][4 * g4 + 2] * inv);
            o.w = f2bf(o2[vh][4 * g4 + 3] * inv);
            const int dvb = 8 * g4 + 4 * hl + 32 * vh;
            *(ushort4*)&AO[(size_t)(b * 2048 + qrow) * 1024 + h * 64 + dvb] = o;
        }
}

// ---------------------------------------------------------------------------
extern "C" void kernel_launch(void* const* d_in, const int* in_sizes, int n_in,
                              void* d_out, int out_size, void* d_ws, size_t ws_size,
                              hipStream_t stream) {
    const float* q_f  = (const float*)d_in[0];
    const float* k_f  = (const float*)d_in[1];
    const float* v_f  = (const float*)d_in[2];
    const float* Wq_w = (const float*)d_in[3];
    const float* Wq_b = (const float*)d_in[4];
    const float* Wk_w = (const float*)d_in[5];
    const float* Wk_b = (const float*)d_in[6];
    const float* Wv_w = (const float*)d_in[7];
    const float* Wv_b = (const float*)d_in[8];
    const float* Wo_w = (const float*)d_in[9];
    const float* Wo_b = (const float*)d_in[10];
    float* out = (float*)d_out;
    char* ws = (char*)d_ws;

    const size_t MB = 1ull << 20;
    ushort* qb  = (ushort*)(ws);                 // 16 MB
    ushort* kb  = (ushort*)(ws + 16 * MB);       // 16 MB
    ushort* vb  = (ushort*)(ws + 32 * MB);       // 16 MB
    ushort* WqT = (ushort*)(ws + 48 * MB);       // 2 MB
    ushort* WkT = (ushort*)(ws + 50 * MB);       // 2 MB
    ushort* WvT = (ushort*)(ws + 52 * MB);       // 2 MB
    ushort* WoT = (ushort*)(ws + 54 * MB);       // 2 MB
    ushort* Qp  = (ushort*)(ws + 56 * MB);       // 16 MB
    ushort* Kp  = (ushort*)(ws + 72 * MB);       // 16 MB
    ushort* Vt  = (ushort*)(ws + 88 * MB);       // 16 MB  (end: 104 MB)
    ushort* AO  = qb;                            // reuse (qb dead after stage 2)

    const int n8 = (4 * 2048 * 1024) / 8;
    prep<<<dim3(1024, 4), 256, 0, stream>>>(q_f, k_f, v_f, Wq_w, Wk_w, Wv_w, Wo_w,
                                            qb, kb, vb, WqT, WkT, WvT, WoT, n8);

    // fold attention scale (1/sqrt(2048)) and log2(e) into Q projection
    constexpr float QSCALE = (float)(1.4426950408889634 / 45.254833995939045);

    gemm_qkv<<<dim3(512, 3), 256, 0, stream>>>(qb, kb, vb, WqT, WkT, WvT,
                                               Wq_b, Wk_b, Wv_b, Qp, Kp, Vt, QSCALE);

    attn_kernel<<<512, 512, 0, stream>>>(Qp, Kp, Vt, AO);

    gemm_out<<<512, 256, 0, stream>>>(AO, WoT, Wo_b, out);
}